// Round 6
// baseline (433.864 us; speedup 1.0000x reference)
//
#include <hip/hip_runtime.h>

#define D 256
#define B 128
#define S 64
#define L 32
#define K 32
#define KH 16
#define NW 16     // waves per recurrence block (1024 threads), 16 cols/wave
#define HSTR 260  // u16 stride: 520B

typedef short bf16x8 __attribute__((ext_vector_type(8)));  // 8 bf16 in 4 VGPRs
typedef float f32x4 __attribute__((ext_vector_type(4)));
typedef unsigned short u16;

__device__ __forceinline__ u16 f2bf(float f) {   // RNE float->bf16 bits
    unsigned u = __float_as_uint(f);
    u += 0x7fffu + ((u >> 16) & 1u);
    return (u16)(u >> 16);
}
__device__ __forceinline__ float bf2f(u16 h) {
    return __uint_as_float(((unsigned)h) << 16);
}

// ---------------------------------------------------------------------------
// sent_mask extraction, robust to bool shipped as 1-byte or int32.
// ---------------------------------------------------------------------------
__global__ void mask_kernel(const void* mraw, int* mask_out) {
    __shared__ int flag;
    const int tid = threadIdx.x;
    if (tid == 0) flag = 0;
    __syncthreads();
    const unsigned int* w32 = (const unsigned int*)mraw;
    int loc = 0;
    for (int i = tid; i < 1024; i += 256)
        if (w32[i] > 1u) loc = 1;
    if (loc) flag = 1;   // benign race
    __syncthreads();
    const bool is_bytes = (flag != 0);
    const unsigned char* b8 = (const unsigned char*)mraw;
    const int* i32 = (const int*)mraw;
    for (int i = tid; i < B * S; i += 256)
        mask_out[i] = is_bytes ? (int)b8[(size_t)i * L] : i32[(size_t)i * L];
}

// ---------------------------------------------------------------------------
// enc_sents[b,s,:] = sum_l E[prgrph[b,s,l], :]  (fp32 out, float4 gathers)
// ---------------------------------------------------------------------------
__global__ __launch_bounds__(256) void embed_kernel(
    const int* __restrict__ prgrph, const float* __restrict__ E,
    float* __restrict__ enc) {
    const int t = threadIdx.x;
    const int g = t >> 6;                // sentence within block
    const int bs = blockIdx.x * 4 + g;
    const int c4 = t & 63;               // float4 column group
    __shared__ int sidx[4][L];
    if (t < 4 * L) sidx[t >> 5][t & 31] = prgrph[(size_t)blockIdx.x * 4 * L + t];
    __syncthreads();
    const float4* E4 = (const float4*)E;
    float4 a = make_float4(0.f, 0.f, 0.f, 0.f);
    #pragma unroll
    for (int l = 0; l < L; ++l) {
        const float4 v = E4[(size_t)sidx[g][l] * (D / 4) + c4];
        a.x += v.x; a.y += v.y; a.z += v.z; a.w += v.w;
    }
    *(float4*)&enc[(size_t)bs * D + c4 * 4] = a;
}

// ---------------------------------------------------------------------------
// O[r,:] = A[r,:] @ Bm, 32 rows/block (enc@W and keys@V).
// ---------------------------------------------------------------------------
__global__ __launch_bounds__(256) void gemm_f32_kernel(
    const float* __restrict__ A, const float* __restrict__ Bm,
    float* __restrict__ O) {
    const int row0 = blockIdx.x * 32;
    const int t = threadIdx.x, wave = t >> 6, lane = t & 63;
    __shared__ float a_s[32 * D];
    const float4* Ag = (const float4*)(A + (size_t)row0 * D);
    float4* As4 = (float4*)a_s;
    for (int i = t; i < 32 * D / 4; i += 256) As4[i] = Ag[i];
    __syncthreads();
    const int r0 = wave * 8, c0 = lane * 4;
    float4 acc[8];
    #pragma unroll
    for (int i = 0; i < 8; ++i) acc[i] = make_float4(0.f, 0.f, 0.f, 0.f);
    for (int d = 0; d < D; d += 4) {
        float4 av[8];
        #pragma unroll
        for (int i = 0; i < 8; ++i) av[i] = *(const float4*)&a_s[(r0 + i) * D + d];
        #pragma unroll
        for (int j = 0; j < 4; ++j) {
            const float4 w = *(const float4*)(Bm + (size_t)(d + j) * D + c0);
            #pragma unroll
            for (int i = 0; i < 8; ++i) {
                const float a = (j == 0) ? av[i].x : (j == 1) ? av[i].y
                              : (j == 2) ? av[i].z : av[i].w;
                acc[i].x += a * w.x; acc[i].y += a * w.y;
                acc[i].z += a * w.z; acc[i].w += a * w.w;
            }
        }
    }
    #pragma unroll
    for (int i = 0; i < 8; ++i)
        *(float4*)&O[(size_t)(row0 + r0 + i) * D + c0] = acc[i];
}

// ---------------------------------------------------------------------------
// ek[b,s,k] = enc[b,s,:] . keys[b,k,:]
// ---------------------------------------------------------------------------
__global__ __launch_bounds__(256) void ek_kernel(
    const float* __restrict__ enc, const float* __restrict__ keys,
    float* __restrict__ ek) {
    const int b = blockIdx.x, t = threadIdx.x;
    __shared__ float ks[K][D + 4];
    const float4* kg = (const float4*)(keys + (size_t)b * K * D);
    for (int i = t; i < K * D / 4; i += 256)
        *(float4*)&ks[i >> 6][(i & 63) * 4] = kg[i];
    __syncthreads();
    const int s = t >> 2, kq = t & 3;          // k = kq + 4j
    const float4* e4 = (const float4*)(enc + (size_t)(b * S + s) * D);
    float acc[8];
    #pragma unroll
    for (int j = 0; j < 8; ++j) acc[j] = 0.f;
    for (int d4 = 0; d4 < D / 4; ++d4) {
        const float4 e = e4[d4];
        #pragma unroll
        for (int j = 0; j < 8; ++j) {
            const float4 kv = *(const float4*)&ks[kq + 4 * j][d4 * 4];
            acc[j] += e.x * kv.x + e.y * kv.y + e.z * kv.z + e.w * kv.w;
        }
    }
    #pragma unroll
    for (int j = 0; j < 8; ++j)
        ek[(size_t)(b * S + s) * K + kq + 4 * j] = acc[j];
}

// ---------------------------------------------------------------------------
// Recurrence. Block = (b, 16-row half of K); 1024 threads = 16 waves; wave w
// owns cols [16w, 16w+16) = ONE 16x16 MFMA tile. Lane (n=lane&15, quad=lane>>4).
// C/D: row=quad*4+reg, col=16w+n. U hi/lo B-frags in regs: 64 VGPR/lane at
// NW=16 -> total live ~115 < 128-reg cap at 4 waves/SIMD -> NO SPILL (R5's
// 60 MB scratch WRITE_SIZE was U spilling at the 128-reg arch cap).
// Gate dot e_s.h_{s-1} in fp32 VALU at end of prev step (piggybacks on the
// single barrier). eWc/ekv reloaded in-place after last use (no double-buffer
// regs). h double-buffered bf16 hi/lo planes in LDS; ONE barrier/step.
// ---------------------------------------------------------------------------
__global__ __launch_bounds__(1024, 4) void recur_kernel(
    const float* __restrict__ enc, const float* __restrict__ eWp,
    const float* __restrict__ keysV, const float* __restrict__ ek,
    const float* __restrict__ U, const int* __restrict__ mask,
    float* __restrict__ out) {
    const int b  = blockIdx.x >> 1;
    const int kh = (blockIdx.x & 1) * KH;
    const int t = threadIdx.x;
    const int wave = t >> 6, lane = t & 63;
    const int n = lane & 15, quad = lane >> 4;
    const int col = wave * 16 + n;

    __shared__ u16 hHi[2][KH][HSTR];     // 2 x 8.1 KB
    __shared__ u16 hLo[2][KH][HSTR];
    __shared__ float redN[2][KH][NW];    // norm partials per wave
    __shared__ float redG[2][KH][NW];    // gate-dot partials per wave

    // ---- preload U B-fragments (hi/lo): 8 kt x 4 VGPR x 2 = 64 VGPRs ----
    bf16x8 Uhi[8], Ulo[8];
    #pragma unroll
    for (int kt = 0; kt < 8; ++kt) {
        #pragma unroll
        for (int j = 0; j < 8; ++j) {
            const int k = kt * 32 + quad * 8 + j;
            const float u = U[(size_t)k * D + col];
            const u16 h16 = f2bf(u);
            Uhi[kt][j] = (short)h16;
            Ulo[kt][j] = (short)f2bf(u - bf2f(h16));
        }
    }

    // ---- per-lane state (1 col per lane) ----
    float upv[4];          // unnormalized h rows; actual h = rn[reg]*upv
    float rn[4];
    float keysVc[4];
    #pragma unroll
    for (int reg = 0; reg < 4; ++reg) {
        rn[reg] = 1.f;
        upv[reg] = 0.f;
        keysVc[reg] = keysV[(size_t)(b * K + kh + quad * 4 + reg) * D + col];
    }

    // ---- active-step bitmask (uniform across waves) ----
    const int* bm = mask + b * S;
    unsigned long long rem = __ballot(bm[lane & 63] != 0);

    float eWc = 0.f;
    float4 ekv = make_float4(0.f, 0.f, 0.f, 0.f);
    if (rem) {      // first active step's invariants (e itself not needed: h=0)
        const int s0 = (int)__builtin_ctzll(rem);
        eWc = eWp[(size_t)(b * S + s0) * D + col];
        ekv = *(const float4*)(ek + (size_t)(b * S + s0) * K + kh + quad * 4);
    }

    int p = 0, q = 0;
    bool first = true;
    while (rem) {
        rem &= rem - 1;
        const int sn = rem ? (int)__builtin_ctzll(rem) : -1;

        // ---- issue next-step e load early (cover latency with MFMA) ----
        float e_n = 0.f;
        if (sn >= 0) e_n = enc[(size_t)(b * S + sn) * D + col];

        // ---- MFMA: acc = upv_prev @ U (3-term bf16 split, 3 indep chains) ----
        f32x4 acc0 = {0.f,0.f,0.f,0.f}, acc1 = {0.f,0.f,0.f,0.f},
              acc2 = {0.f,0.f,0.f,0.f};
        if (!first) {
            #pragma unroll
            for (int kt = 0; kt < 8; ++kt) {
                const bf16x8 ahi = *(const bf16x8*)&hHi[p][n][kt * 32 + quad * 8];
                const bf16x8 alo = *(const bf16x8*)&hLo[p][n][kt * 32 + quad * 8];
                acc0 = __builtin_amdgcn_mfma_f32_16x16x32_bf16(ahi, Uhi[kt], acc0, 0, 0, 0);
                acc1 = __builtin_amdgcn_mfma_f32_16x16x32_bf16(alo, Uhi[kt], acc1, 0, 0, 0);
                acc2 = __builtin_amdgcn_mfma_f32_16x16x32_bf16(ahi, Ulo[kt], acc2, 0, 0, 0);
            }
        }

        // ---- gate: logit = rn * sum_w redG + ek  (dot done last step) ----
        float gate[4];
        #pragma unroll
        for (int reg = 0; reg < 4; ++reg) {
            const float ekb = (reg == 0) ? ekv.x : (reg == 1) ? ekv.y
                            : (reg == 2) ? ekv.z : ekv.w;
            float g = ekb;
            if (!first) {
                const float* rg = redG[q ^ 1][quad * 4 + reg];
                float sg = 0.f;
                #pragma unroll
                for (int w4 = 0; w4 < NW / 4; ++w4) {
                    const float4 g4 = *(const float4*)(rg + w4 * 4);
                    sg += g4.x + g4.y + g4.z + g4.w;
                }
                g += rn[reg] * sg;
            }
            gate[reg] = 1.f / (1.f + __expf(-g));
        }

        // ---- update + split-write new h + norm partial ----
        const int pw = p ^ 1;
        float pn[4];
        #pragma unroll
        for (int reg = 0; reg < 4; ++reg) {
            const int row = quad * 4 + reg;
            const float asum = acc0[reg] + acc1[reg] + acc2[reg];
            float ht = rn[reg] * asum + keysVc[reg] + eWc;
            ht = fmaxf(ht, 0.f);
            const float u2 = rn[reg] * upv[reg] + gate[reg] * ht;
            upv[reg] = u2;
            pn[reg] = u2 * u2;
            const u16 hi = f2bf(u2);
            hHi[pw][row][col] = hi;
            hLo[pw][row][col] = f2bf(u2 - bf2f(hi));
        }

        // ---- reload step-invariants for next step IN PLACE (last use passed) ----
        if (sn >= 0) {
            eWc = eWp[(size_t)(b * S + sn) * D + col];
            ekv = *(const float4*)(ek + (size_t)(b * S + sn) * K + kh + quad * 4);
        }

        // ---- gate-dot partial for NEXT step: upv_new . e_next (fp32) ----
        float gd[4];
        #pragma unroll
        for (int reg = 0; reg < 4; ++reg) gd[reg] = upv[reg] * e_n;
        #pragma unroll
        for (int m = 1; m <= 8; m <<= 1) {
            #pragma unroll
            for (int reg = 0; reg < 4; ++reg) {
                pn[reg] += __shfl_xor(pn[reg], m);
                gd[reg] += __shfl_xor(gd[reg], m);
            }
        }
        if (n == 0) {
            #pragma unroll
            for (int reg = 0; reg < 4; ++reg) {
                redN[q][quad * 4 + reg][wave] = pn[reg];
                redG[q][quad * 4 + reg][wave] = gd[reg];
            }
        }

        __syncthreads();   // the ONLY barrier

        #pragma unroll
        for (int reg = 0; reg < 4; ++reg) {
            const float* rp = redN[q][quad * 4 + reg];
            float ss = 0.f;
            #pragma unroll
            for (int w4 = 0; w4 < NW / 4; ++w4) {
                const float4 r4 = *(const float4*)(rp + w4 * 4);
                ss += r4.x + r4.y + r4.z + r4.w;
            }
            rn[reg] = rsqrtf(fmaxf(ss, 1e-12f));
        }
        p ^= 1; q ^= 1; first = false;
    }

    #pragma unroll
    for (int reg = 0; reg < 4; ++reg)
        out[(size_t)(b * K + kh + quad * 4 + reg) * D + col] = rn[reg] * upv[reg];
}

extern "C" void kernel_launch(void* const* d_in, const int* in_sizes, int n_in,
                              void* d_out, int out_size, void* d_ws, size_t ws_size,
                              hipStream_t stream) {
    const int*   prgrph = (const int*)d_in[0];
    const void*  pmask  = d_in[1];
    const float* keys   = (const float*)d_in[2];
    const float* E      = (const float*)d_in[3];
    const float* U      = (const float*)d_in[4];
    const float* V      = (const float*)d_in[5];
    const float* W      = (const float*)d_in[6];
    float* out = (float*)d_out;

    // workspace layout (fp32 unless noted)
    float* ws_enc   = (float*)d_ws;                          // B*S*D  (8 MB)
    float* ws_eW    = ws_enc + (size_t)B * S * D;            // B*S*D  (8 MB)
    float* ws_keysV = ws_eW  + (size_t)B * S * D;            // B*K*D  (4 MB)
    float* ws_ek    = ws_keysV + (size_t)B * K * D;          // B*S*K  (1 MB)
    int*   ws_mask  = (int*)(ws_ek + (size_t)B * S * K);     // B*S

    mask_kernel<<<1, 256, 0, stream>>>(pmask, ws_mask);
    embed_kernel<<<(B * S) / 4, 256, 0, stream>>>(prgrph, E, ws_enc);
    gemm_f32_kernel<<<(B * S) / 32, 256, 0, stream>>>(ws_enc, W, ws_eW);
    gemm_f32_kernel<<<(B * K) / 32, 256, 0, stream>>>(keys, V, ws_keysV);
    ek_kernel<<<B, 256, 0, stream>>>(ws_enc, keys, ws_ek);
    recur_kernel<<<B * (K / KH), 1024, 0, stream>>>(
        ws_enc, ws_eW, ws_keysV, ws_ek, U, ws_mask, out);
}

// Round 7
// 364.905 us; speedup vs baseline: 1.1890x; 1.1890x over previous
//
#include <hip/hip_runtime.h>

#define D 256
#define B 128
#define S 64
#define L 32
#define K 32
#define KH 16
#define NW 4      // waves per recurrence block (256 threads), 64 cols/wave
#define NSUB 4    // 16-col sub-tiles per wave
#define HSTR 260  // u16 stride: 520B -> A-frag b128 reads exactly 8 acc/bank (free)

typedef short bf16x8 __attribute__((ext_vector_type(8)));  // 8 bf16 in 4 VGPRs
typedef float f32x4 __attribute__((ext_vector_type(4)));
typedef unsigned short u16;

__device__ __forceinline__ u16 f2bf(float f) {   // RNE float->bf16 bits
    unsigned u = __float_as_uint(f);
    u += 0x7fffu + ((u >> 16) & 1u);
    return (u16)(u >> 16);
}
__device__ __forceinline__ float bf2f(u16 h) {
    return __uint_as_float(((unsigned)h) << 16);
}

// ---------------------------------------------------------------------------
// sent_mask extraction, robust to bool shipped as 1-byte or int32.
// ---------------------------------------------------------------------------
__global__ void mask_kernel(const void* mraw, int* mask_out) {
    __shared__ int flag;
    const int tid = threadIdx.x;
    if (tid == 0) flag = 0;
    __syncthreads();
    const unsigned int* w32 = (const unsigned int*)mraw;
    int loc = 0;
    for (int i = tid; i < 1024; i += 256)
        if (w32[i] > 1u) loc = 1;
    if (loc) flag = 1;   // benign race
    __syncthreads();
    const bool is_bytes = (flag != 0);
    const unsigned char* b8 = (const unsigned char*)mraw;
    const int* i32 = (const int*)mraw;
    for (int i = tid; i < B * S; i += 256)
        mask_out[i] = is_bytes ? (int)b8[(size_t)i * L] : i32[(size_t)i * L];
}

// ---------------------------------------------------------------------------
// enc_sents[b,s,:] = sum_l E[prgrph[b,s,l], :]  (fp32 out, float4 gathers)
// ---------------------------------------------------------------------------
__global__ __launch_bounds__(256) void embed_kernel(
    const int* __restrict__ prgrph, const float* __restrict__ E,
    float* __restrict__ enc) {
    const int t = threadIdx.x;
    const int g = t >> 6;                // sentence within block
    const int bs = blockIdx.x * 4 + g;
    const int c4 = t & 63;               // float4 column group
    __shared__ int sidx[4][L];
    if (t < 4 * L) sidx[t >> 5][t & 31] = prgrph[(size_t)blockIdx.x * 4 * L + t];
    __syncthreads();
    const float4* E4 = (const float4*)E;
    float4 a = make_float4(0.f, 0.f, 0.f, 0.f);
    #pragma unroll
    for (int l = 0; l < L; ++l) {
        const float4 v = E4[(size_t)sidx[g][l] * (D / 4) + c4];
        a.x += v.x; a.y += v.y; a.z += v.z; a.w += v.w;
    }
    *(float4*)&enc[(size_t)bs * D + c4 * 4] = a;
}

// ---------------------------------------------------------------------------
// O[r,:] = A[r,:] @ Bm, 32 rows/block (enc@W and keys@V).
// ---------------------------------------------------------------------------
__global__ __launch_bounds__(256) void gemm_f32_kernel(
    const float* __restrict__ A, const float* __restrict__ Bm,
    float* __restrict__ O) {
    const int row0 = blockIdx.x * 32;
    const int t = threadIdx.x, wave = t >> 6, lane = t & 63;
    __shared__ float a_s[32 * D];
    const float4* Ag = (const float4*)(A + (size_t)row0 * D);
    float4* As4 = (float4*)a_s;
    for (int i = t; i < 32 * D / 4; i += 256) As4[i] = Ag[i];
    __syncthreads();
    const int r0 = wave * 8, c0 = lane * 4;
    float4 acc[8];
    #pragma unroll
    for (int i = 0; i < 8; ++i) acc[i] = make_float4(0.f, 0.f, 0.f, 0.f);
    for (int d = 0; d < D; d += 4) {
        float4 av[8];
        #pragma unroll
        for (int i = 0; i < 8; ++i) av[i] = *(const float4*)&a_s[(r0 + i) * D + d];
        #pragma unroll
        for (int j = 0; j < 4; ++j) {
            const float4 w = *(const float4*)(Bm + (size_t)(d + j) * D + c0);
            #pragma unroll
            for (int i = 0; i < 8; ++i) {
                const float a = (j == 0) ? av[i].x : (j == 1) ? av[i].y
                              : (j == 2) ? av[i].z : av[i].w;
                acc[i].x += a * w.x; acc[i].y += a * w.y;
                acc[i].z += a * w.z; acc[i].w += a * w.w;
            }
        }
    }
    #pragma unroll
    for (int i = 0; i < 8; ++i)
        *(float4*)&O[(size_t)(row0 + r0 + i) * D + c0] = acc[i];
}

// ---------------------------------------------------------------------------
// ek[b,s,k] = enc[b,s,:] . keys[b,k,:]
// ---------------------------------------------------------------------------
__global__ __launch_bounds__(256) void ek_kernel(
    const float* __restrict__ enc, const float* __restrict__ keys,
    float* __restrict__ ek) {
    const int b = blockIdx.x, t = threadIdx.x;
    __shared__ float ks[K][D + 4];
    const float4* kg = (const float4*)(keys + (size_t)b * K * D);
    for (int i = t; i < K * D / 4; i += 256)
        *(float4*)&ks[i >> 6][(i & 63) * 4] = kg[i];
    __syncthreads();
    const int s = t >> 2, kq = t & 3;          // k = kq + 4j
    const float4* e4 = (const float4*)(enc + (size_t)(b * S + s) * D);
    float acc[8];
    #pragma unroll
    for (int j = 0; j < 8; ++j) acc[j] = 0.f;
    for (int d4 = 0; d4 < D / 4; ++d4) {
        const float4 e = e4[d4];
        #pragma unroll
        for (int j = 0; j < 8; ++j) {
            const float4 kv = *(const float4*)&ks[kq + 4 * j][d4 * 4];
            acc[j] += e.x * kv.x + e.y * kv.y + e.z * kv.z + e.w * kv.w;
        }
    }
    #pragma unroll
    for (int j = 0; j < 8; ++j)
        ek[(size_t)(b * S + s) * K + kq + 4 * j] = acc[j];
}

// ---------------------------------------------------------------------------
// Recurrence. Block = (b, 16-row half of K); 256 threads = 4 waves; wave w
// owns cols [64w, 64w+64) = 4 MFMA sub-tiles. Lane (n=lane&15, quad=lane>>4).
// C/D: row=quad*4+reg, col=64w+16sub+n.
// REGISTER BUDGET is the whole game (R5/R6 post-mortems): demand ~360 unified
// regs (U hi/lo frags 256 + acc 48 + state ~55) only fits without spill at
// the 512/wave budget -> 256 threads, __launch_bounds__(256,1), 1 wave/SIMD.
// R2 (same occupancy, demand ~470) ran 169us WITH ~22MB spill; this cuts
// demand ~110 regs via R5's gate trick: e_s.h_{s-1} computed fp32 VALU at the
// END of the prev step against early-loaded e_next, shuffle-reduced, wave
// partials through LDS, summed post-barrier. No accE MFMAs, no e-fragments.
// h double-buffered bf16 hi/lo planes in LDS; ONE barrier/step.
// ---------------------------------------------------------------------------
__global__ __launch_bounds__(256, 1) void recur_kernel(
    const float* __restrict__ enc, const float* __restrict__ eWp,
    const float* __restrict__ keysV, const float* __restrict__ ek,
    const float* __restrict__ U, const int* __restrict__ mask,
    float* __restrict__ out) {
    const int b  = blockIdx.x >> 1;
    const int kh = (blockIdx.x & 1) * KH;
    const int t = threadIdx.x;
    const int wave = t >> 6, lane = t & 63;
    const int n = lane & 15, quad = lane >> 4;

    __shared__ u16 hHi[2][KH][HSTR];     // 2 x 8.1 KB
    __shared__ u16 hLo[2][KH][HSTR];
    __shared__ float redN[2][KH][NW];    // norm partials per wave
    __shared__ float redG[2][KH][NW];    // gate-dot partials per wave

    // ---- preload U B-fragments (hi/lo): 4 subs x 8 kt x 4 VGPR x 2 = 256 ----
    bf16x8 Uhi[NSUB][8], Ulo[NSUB][8];
    #pragma unroll
    for (int sub = 0; sub < NSUB; ++sub) {
        const int col = wave * 64 + sub * 16 + n;
        #pragma unroll
        for (int kt = 0; kt < 8; ++kt) {
            #pragma unroll
            for (int j = 0; j < 8; ++j) {
                const int k = kt * 32 + quad * 8 + j;
                const float u = U[(size_t)k * D + col];
                const u16 h16 = f2bf(u);
                Uhi[sub][kt][j] = (short)h16;
                Ulo[sub][kt][j] = (short)f2bf(u - bf2f(h16));
            }
        }
    }

    // ---- per-lane state ----
    float upv[4][NSUB];          // unnormalized h rows; actual h = rn[reg]*upv
    float rn[4];
    float keysVc[4][NSUB];
    #pragma unroll
    for (int reg = 0; reg < 4; ++reg) {
        rn[reg] = 1.f;
        const size_t base = (size_t)(b * K + kh + quad * 4 + reg) * D;
        #pragma unroll
        for (int sub = 0; sub < NSUB; ++sub) {
            upv[reg][sub] = 0.f;
            keysVc[reg][sub] = keysV[base + wave * 64 + sub * 16 + n];
        }
    }

    // ---- active-step bitmask (uniform across waves) ----
    const int* bm = mask + b * S;
    unsigned long long rem = __ballot(bm[lane & 63] != 0);

    float eWc[NSUB];
    float4 ekv = make_float4(0.f, 0.f, 0.f, 0.f);
    #pragma unroll
    for (int sub = 0; sub < NSUB; ++sub) eWc[sub] = 0.f;
    if (rem) {      // first active step's invariants (e itself not needed: h=0)
        const int s0 = (int)__builtin_ctzll(rem);
        const size_t eo = (size_t)(b * S + s0) * D;
        #pragma unroll
        for (int sub = 0; sub < NSUB; ++sub)
            eWc[sub] = eWp[eo + wave * 64 + sub * 16 + n];
        ekv = *(const float4*)(ek + (size_t)(b * S + s0) * K + kh + quad * 4);
    }

    int p = 0, q = 0;
    bool first = true;
    while (rem) {
        rem &= rem - 1;
        const int sn = rem ? (int)__builtin_ctzll(rem) : -1;

        // ---- issue next-step e load early (cover latency with MFMA) ----
        float e_n[NSUB];
        #pragma unroll
        for (int sub = 0; sub < NSUB; ++sub) e_n[sub] = 0.f;
        if (sn >= 0) {
            const size_t eo = (size_t)(b * S + sn) * D;
            #pragma unroll
            for (int sub = 0; sub < NSUB; ++sub)
                e_n[sub] = enc[eo + wave * 64 + sub * 16 + n];
        }

        // ---- MFMA: acc = upv_prev @ U (3-term bf16 split, 12 indep chains) ----
        f32x4 acc[NSUB][3];
        #pragma unroll
        for (int sub = 0; sub < NSUB; ++sub)
            #pragma unroll
            for (int c = 0; c < 3; ++c) acc[sub][c] = (f32x4){0.f, 0.f, 0.f, 0.f};
        if (!first) {
            #pragma unroll
            for (int kt = 0; kt < 8; ++kt) {
                const bf16x8 ahi = *(const bf16x8*)&hHi[p][n][kt * 32 + quad * 8];
                const bf16x8 alo = *(const bf16x8*)&hLo[p][n][kt * 32 + quad * 8];
                #pragma unroll
                for (int sub = 0; sub < NSUB; ++sub) {
                    acc[sub][0] = __builtin_amdgcn_mfma_f32_16x16x32_bf16(ahi, Uhi[sub][kt], acc[sub][0], 0, 0, 0);
                    acc[sub][1] = __builtin_amdgcn_mfma_f32_16x16x32_bf16(alo, Uhi[sub][kt], acc[sub][1], 0, 0, 0);
                    acc[sub][2] = __builtin_amdgcn_mfma_f32_16x16x32_bf16(ahi, Ulo[sub][kt], acc[sub][2], 0, 0, 0);
                }
            }
        }

        // ---- gate: logit = rn * sum_w redG + ek  (dot done last step) ----
        float gate[4];
        #pragma unroll
        for (int reg = 0; reg < 4; ++reg) {
            const float ekb = (reg == 0) ? ekv.x : (reg == 1) ? ekv.y
                            : (reg == 2) ? ekv.z : ekv.w;
            float g = ekb;
            if (!first) {
                const float4 g4 = *(const float4*)redG[q ^ 1][quad * 4 + reg];
                g += rn[reg] * (g4.x + g4.y + g4.z + g4.w);
            }
            gate[reg] = 1.f / (1.f + __expf(-g));
        }

        // ---- update + split-write new h + norm partial ----
        const int pw = p ^ 1;
        float pn[4];
        #pragma unroll
        for (int reg = 0; reg < 4; ++reg) {
            const int row = quad * 4 + reg;
            float sq = 0.f;
            #pragma unroll
            for (int sub = 0; sub < NSUB; ++sub) {
                const float asum = acc[sub][0][reg] + acc[sub][1][reg] + acc[sub][2][reg];
                float ht = rn[reg] * asum + keysVc[reg][sub] + eWc[sub];
                ht = fmaxf(ht, 0.f);
                const float u2 = rn[reg] * upv[reg][sub] + gate[reg] * ht;
                upv[reg][sub] = u2;
                sq += u2 * u2;
                const u16 hi = f2bf(u2);
                const int col = wave * 64 + sub * 16 + n;
                hHi[pw][row][col] = hi;
                hLo[pw][row][col] = f2bf(u2 - bf2f(hi));
            }
            pn[reg] = sq;
        }

        // ---- reload step-invariants for next step IN PLACE (last use passed) ----
        if (sn >= 0) {
            const size_t eo = (size_t)(b * S + sn) * D;
            #pragma unroll
            for (int sub = 0; sub < NSUB; ++sub)
                eWc[sub] = eWp[eo + wave * 64 + sub * 16 + n];
            ekv = *(const float4*)(ek + (size_t)(b * S + sn) * K + kh + quad * 4);
        }

        // ---- gate-dot partial for NEXT step: upv_new . e_next (fp32) ----
        float gd[4];
        #pragma unroll
        for (int reg = 0; reg < 4; ++reg) {
            float v = 0.f;
            #pragma unroll
            for (int sub = 0; sub < NSUB; ++sub)
                v += upv[reg][sub] * e_n[sub];
            gd[reg] = v;
        }
        #pragma unroll
        for (int m = 1; m <= 8; m <<= 1) {
            #pragma unroll
            for (int reg = 0; reg < 4; ++reg) {
                pn[reg] += __shfl_xor(pn[reg], m);
                gd[reg] += __shfl_xor(gd[reg], m);
            }
        }
        if (n == 0) {
            #pragma unroll
            for (int reg = 0; reg < 4; ++reg) {
                redN[q][quad * 4 + reg][wave] = pn[reg];
                redG[q][quad * 4 + reg][wave] = gd[reg];
            }
        }

        __syncthreads();   // the ONLY barrier

        #pragma unroll
        for (int reg = 0; reg < 4; ++reg) {
            const float4 r4 = *(const float4*)redN[q][quad * 4 + reg];
            rn[reg] = rsqrtf(fmaxf(r4.x + r4.y + r4.z + r4.w, 1e-12f));
        }
        p ^= 1; q ^= 1; first = false;
    }

    #pragma unroll
    for (int reg = 0; reg < 4; ++reg) {
        const size_t base = (size_t)(b * K + kh + quad * 4 + reg) * D;
        #pragma unroll
        for (int sub = 0; sub < NSUB; ++sub)
            out[base + wave * 64 + sub * 16 + n] = rn[reg] * upv[reg][sub];
    }
}

extern "C" void kernel_launch(void* const* d_in, const int* in_sizes, int n_in,
                              void* d_out, int out_size, void* d_ws, size_t ws_size,
                              hipStream_t stream) {
    const int*   prgrph = (const int*)d_in[0];
    const void*  pmask  = d_in[1];
    const float* keys   = (const float*)d_in[2];
    const float* E      = (const float*)d_in[3];
    const float* U      = (const float*)d_in[4];
    const float* V      = (const float*)d_in[5];
    const float* W      = (const float*)d_in[6];
    float* out = (float*)d_out;

    // workspace layout (fp32 unless noted)
    float* ws_enc   = (float*)d_ws;                          // B*S*D  (8 MB)
    float* ws_eW    = ws_enc + (size_t)B * S * D;            // B*S*D  (8 MB)
    float* ws_keysV = ws_eW  + (size_t)B * S * D;            // B*K*D  (4 MB)
    float* ws_ek    = ws_keysV + (size_t)B * K * D;          // B*S*K  (1 MB)
    int*   ws_mask  = (int*)(ws_ek + (size_t)B * S * K);     // B*S

    mask_kernel<<<1, 256, 0, stream>>>(pmask, ws_mask);
    embed_kernel<<<(B * S) / 4, 256, 0, stream>>>(prgrph, E, ws_enc);
    gemm_f32_kernel<<<(B * S) / 32, 256, 0, stream>>>(ws_enc, W, ws_eW);
    gemm_f32_kernel<<<(B * K) / 32, 256, 0, stream>>>(keys, V, ws_keysV);
    ek_kernel<<<B, 256, 0, stream>>>(ws_enc, keys, ws_ek);
    recur_kernel<<<B * (K / KH), 256, 0, stream>>>(
        ws_enc, ws_eW, ws_keysV, ws_ek, U, ws_mask, out);
}

// Round 8
// 344.152 us; speedup vs baseline: 1.2607x; 1.0603x over previous
//
#include <hip/hip_runtime.h>

#define D 256
#define B 128
#define S 64
#define L 32
#define K 32
#define KH 16
#define NW 4      // waves per recurrence block (256 threads), 64 cols/wave
#define NSUB 4    // 16-col sub-tiles per wave
#define HSTR 260  // u16 stride (proven 0-conflict in R7)

typedef _Float16 f16x8 __attribute__((ext_vector_type(8)));  // 8 f16 in 4 VGPRs
typedef float f32x4 __attribute__((ext_vector_type(4)));
typedef unsigned short u16;

__device__ __forceinline__ u16 h_bits(_Float16 h) {
    union { _Float16 h; u16 u; } x; x.h = h; return x.u;
}

// ---------------------------------------------------------------------------
// sent_mask extraction, robust to bool shipped as 1-byte or int32.
// ---------------------------------------------------------------------------
__global__ void mask_kernel(const void* mraw, int* mask_out) {
    __shared__ int flag;
    const int tid = threadIdx.x;
    if (tid == 0) flag = 0;
    __syncthreads();
    const unsigned int* w32 = (const unsigned int*)mraw;
    int loc = 0;
    for (int i = tid; i < 1024; i += 256)
        if (w32[i] > 1u) loc = 1;
    if (loc) flag = 1;   // benign race
    __syncthreads();
    const bool is_bytes = (flag != 0);
    const unsigned char* b8 = (const unsigned char*)mraw;
    const int* i32 = (const int*)mraw;
    for (int i = tid; i < B * S; i += 256)
        mask_out[i] = is_bytes ? (int)b8[(size_t)i * L] : i32[(size_t)i * L];
}

// ---------------------------------------------------------------------------
// Fused preprocessing: block = (b, 32-sentence half). Gathers enc rows into
// LDS (embed), writes enc, runs the proven 32-row gemm vs W -> eW, then
// ek[s,k] = enc[s,:].keys[b,k,:]. Replaces 3 kernels with 1.
// ---------------------------------------------------------------------------
__global__ __launch_bounds__(256) void prep_kernel(
    const int* __restrict__ prgrph, const float* __restrict__ E,
    const float* __restrict__ W, const float* __restrict__ keys,
    float* __restrict__ enc, float* __restrict__ eW, float* __restrict__ ek) {
    const int blk = blockIdx.x;
    const int b = blk >> 1;
    const int s0 = (blk & 1) * 32;
    const int t = threadIdx.x, wave = t >> 6, lane = t & 63;
    __shared__ float a_s[32 * D];   // 32 KB: enc rows for this tile
    __shared__ int tok[32 * L];     // 4 KB

    for (int i = t; i < 32 * L; i += 256)
        tok[i] = prgrph[((size_t)b * S + s0) * L + i];
    __syncthreads();

    // ---- embed gather: each float4 slot = sum of 32 embedding float4s ----
    const float4* E4 = (const float4*)E;
    for (int i = t; i < 32 * 64; i += 256) {
        const int r = i >> 6, c4 = i & 63;
        float4 a = make_float4(0.f, 0.f, 0.f, 0.f);
        #pragma unroll 8
        for (int l = 0; l < L; ++l) {
            const float4 v = E4[(size_t)tok[r * L + l] * 64 + c4];
            a.x += v.x; a.y += v.y; a.z += v.z; a.w += v.w;
        }
        *(float4*)&a_s[i * 4] = a;
        *(float4*)&enc[((size_t)b * S + s0 + r) * D + c4 * 4] = a;
    }
    __syncthreads();

    // ---- gemm: a_s @ W -> eW (8 rows x 4 cols per thread) ----
    const int r0 = wave * 8, c0 = lane * 4;
    float4 acc[8];
    #pragma unroll
    for (int i = 0; i < 8; ++i) acc[i] = make_float4(0.f, 0.f, 0.f, 0.f);
    for (int d = 0; d < D; d += 4) {
        float4 av[8];
        #pragma unroll
        for (int i = 0; i < 8; ++i) av[i] = *(const float4*)&a_s[(r0 + i) * D + d];
        #pragma unroll
        for (int j = 0; j < 4; ++j) {
            const float4 w = *(const float4*)(W + (size_t)(d + j) * D + c0);
            #pragma unroll
            for (int i = 0; i < 8; ++i) {
                const float a = (j == 0) ? av[i].x : (j == 1) ? av[i].y
                              : (j == 2) ? av[i].z : av[i].w;
                acc[i].x += a * w.x; acc[i].y += a * w.y;
                acc[i].z += a * w.z; acc[i].w += a * w.w;
            }
        }
    }
    #pragma unroll
    for (int i = 0; i < 8; ++i)
        *(float4*)&eW[((size_t)b * S + s0 + r0 + i) * D + c0] = acc[i];

    // ---- ek: thread -> (k = t&31, 4 sentences) ----
    const int k = t & 31;
    const int rg = (t >> 5) * 4;
    const float4* kr = (const float4*)(keys + ((size_t)b * K + k) * D);
    float e0 = 0.f, e1 = 0.f, e2 = 0.f, e3 = 0.f;
    for (int d4 = 0; d4 < 64; ++d4) {
        const float4 kv = kr[d4];
        const float4 a0 = *(const float4*)&a_s[(rg + 0) * D + d4 * 4];
        const float4 a1 = *(const float4*)&a_s[(rg + 1) * D + d4 * 4];
        const float4 a2 = *(const float4*)&a_s[(rg + 2) * D + d4 * 4];
        const float4 a3 = *(const float4*)&a_s[(rg + 3) * D + d4 * 4];
        e0 += a0.x * kv.x + a0.y * kv.y + a0.z * kv.z + a0.w * kv.w;
        e1 += a1.x * kv.x + a1.y * kv.y + a1.z * kv.z + a1.w * kv.w;
        e2 += a2.x * kv.x + a2.y * kv.y + a2.z * kv.z + a2.w * kv.w;
        e3 += a3.x * kv.x + a3.y * kv.y + a3.z * kv.z + a3.w * kv.w;
    }
    ek[((size_t)b * S + s0 + rg + 0) * K + k] = e0;
    ek[((size_t)b * S + s0 + rg + 1) * K + k] = e1;
    ek[((size_t)b * S + s0 + rg + 2) * K + k] = e2;
    ek[((size_t)b * S + s0 + rg + 3) * K + k] = e3;
}

// ---------------------------------------------------------------------------
// O[r,:] = A[r,:] @ Bm, 32 rows/block (keys@V).
// ---------------------------------------------------------------------------
__global__ __launch_bounds__(256) void gemm_f32_kernel(
    const float* __restrict__ A, const float* __restrict__ Bm,
    float* __restrict__ O) {
    const int row0 = blockIdx.x * 32;
    const int t = threadIdx.x, wave = t >> 6, lane = t & 63;
    __shared__ float a_s[32 * D];
    const float4* Ag = (const float4*)(A + (size_t)row0 * D);
    float4* As4 = (float4*)a_s;
    for (int i = t; i < 32 * D / 4; i += 256) As4[i] = Ag[i];
    __syncthreads();
    const int r0 = wave * 8, c0 = lane * 4;
    float4 acc[8];
    #pragma unroll
    for (int i = 0; i < 8; ++i) acc[i] = make_float4(0.f, 0.f, 0.f, 0.f);
    for (int d = 0; d < D; d += 4) {
        float4 av[8];
        #pragma unroll
        for (int i = 0; i < 8; ++i) av[i] = *(const float4*)&a_s[(r0 + i) * D + d];
        #pragma unroll
        for (int j = 0; j < 4; ++j) {
            const float4 w = *(const float4*)(Bm + (size_t)(d + j) * D + c0);
            #pragma unroll
            for (int i = 0; i < 8; ++i) {
                const float a = (j == 0) ? av[i].x : (j == 1) ? av[i].y
                              : (j == 2) ? av[i].z : av[i].w;
                acc[i].x += a * w.x; acc[i].y += a * w.y;
                acc[i].z += a * w.z; acc[i].w += a * w.w;
            }
        }
    }
    #pragma unroll
    for (int i = 0; i < 8; ++i)
        *(float4*)&O[(size_t)(row0 + r0 + i) * D + c0] = acc[i];
}

// ---------------------------------------------------------------------------
// Recurrence (structure = R7, which passed). Changes:
//  * h stored as ONE f16 LDS plane (was bf16 hi/lo): A-reads + ds_writes
//    halve, MFMA 96->64 per wave (a.Uhi + a.Ulo, U split f16 hi/lo).
//  * U fragments pinned into AGPRs (empty-asm "+a"): arch-VGPR demand drops
//    to ~120 -> no spill (R7 still spilled ~27 regs; arch VGPR cap is 256).
// Accuracy: A quant 2^-11, U split exact to ~2^-21 (worst case 2^-11 if f16
// denormal Ulo flushes) -> ~1e-3 final absmax vs 8.2e-3 threshold.
// ---------------------------------------------------------------------------
__global__ __launch_bounds__(256, 1) void recur_kernel(
    const float* __restrict__ enc, const float* __restrict__ eWp,
    const float* __restrict__ keysV, const float* __restrict__ ek,
    const float* __restrict__ U, const int* __restrict__ mask,
    float* __restrict__ out) {
    const int b  = blockIdx.x >> 1;
    const int kh = (blockIdx.x & 1) * KH;
    const int t = threadIdx.x;
    const int wave = t >> 6, lane = t & 63;
    const int n = lane & 15, quad = lane >> 4;

    __shared__ u16 hF[2][KH][HSTR];      // f16 h planes, double-buffered
    __shared__ float redN[2][KH][NW];
    __shared__ float redG[2][KH][NW];

    // ---- preload U B-fragments (f16 hi/lo), pin into AGPRs ----
    f16x8 Uhi[NSUB][8], Ulo[NSUB][8];
    #pragma unroll
    for (int sub = 0; sub < NSUB; ++sub) {
        const int col = wave * 64 + sub * 16 + n;
        #pragma unroll
        for (int kt = 0; kt < 8; ++kt) {
            #pragma unroll
            for (int j = 0; j < 8; ++j) {
                const int k = kt * 32 + quad * 8 + j;
                const float u = U[(size_t)k * D + col];
                const _Float16 uh = (_Float16)u;
                Uhi[sub][kt][j] = uh;
                Ulo[sub][kt][j] = (_Float16)(u - (float)uh);
            }
        }
    }
    #pragma unroll
    for (int sub = 0; sub < NSUB; ++sub)
        #pragma unroll
        for (int kt = 0; kt < 8; ++kt)
            asm volatile("" : "+a"(Uhi[sub][kt]), "+a"(Ulo[sub][kt]));

    // ---- per-lane state ----
    float upv[4][NSUB];
    float rn[4];
    float keysVc[4][NSUB];
    #pragma unroll
    for (int reg = 0; reg < 4; ++reg) {
        rn[reg] = 1.f;
        const size_t base = (size_t)(b * K + kh + quad * 4 + reg) * D;
        #pragma unroll
        for (int sub = 0; sub < NSUB; ++sub) {
            upv[reg][sub] = 0.f;
            keysVc[reg][sub] = keysV[base + wave * 64 + sub * 16 + n];
        }
    }

    const int* bm = mask + b * S;
    unsigned long long rem = __ballot(bm[lane & 63] != 0);

    float eWc[NSUB];
    float4 ekv = make_float4(0.f, 0.f, 0.f, 0.f);
    #pragma unroll
    for (int sub = 0; sub < NSUB; ++sub) eWc[sub] = 0.f;
    if (rem) {
        const int s0 = (int)__builtin_ctzll(rem);
        const size_t eo = (size_t)(b * S + s0) * D;
        #pragma unroll
        for (int sub = 0; sub < NSUB; ++sub)
            eWc[sub] = eWp[eo + wave * 64 + sub * 16 + n];
        ekv = *(const float4*)(ek + (size_t)(b * S + s0) * K + kh + quad * 4);
    }

    int p = 0, q = 0;
    bool first = true;
    while (rem) {
        rem &= rem - 1;
        const int sn = rem ? (int)__builtin_ctzll(rem) : -1;

        // next-step e loads issued early
        float e_n[NSUB];
        #pragma unroll
        for (int sub = 0; sub < NSUB; ++sub) e_n[sub] = 0.f;
        if (sn >= 0) {
            const size_t eo = (size_t)(b * S + sn) * D;
            #pragma unroll
            for (int sub = 0; sub < NSUB; ++sub)
                e_n[sub] = enc[eo + wave * 64 + sub * 16 + n];
        }

        // ---- MFMA: acc = h_prev @ (Uhi + Ulo), f16, 8 indep chains ----
        f32x4 acc[NSUB][2];
        #pragma unroll
        for (int sub = 0; sub < NSUB; ++sub) {
            acc[sub][0] = (f32x4){0.f, 0.f, 0.f, 0.f};
            acc[sub][1] = (f32x4){0.f, 0.f, 0.f, 0.f};
        }
        if (!first) {
            #pragma unroll
            for (int kt = 0; kt < 8; ++kt) {
                const f16x8 av = *(const f16x8*)&hF[p][n][kt * 32 + quad * 8];
                #pragma unroll
                for (int sub = 0; sub < NSUB; ++sub) {
                    acc[sub][0] = __builtin_amdgcn_mfma_f32_16x16x32_f16(av, Uhi[sub][kt], acc[sub][0], 0, 0, 0);
                    acc[sub][1] = __builtin_amdgcn_mfma_f32_16x16x32_f16(av, Ulo[sub][kt], acc[sub][1], 0, 0, 0);
                }
            }
        }

        // ---- gate ----
        float gate[4];
        #pragma unroll
        for (int reg = 0; reg < 4; ++reg) {
            const float ekb = (reg == 0) ? ekv.x : (reg == 1) ? ekv.y
                            : (reg == 2) ? ekv.z : ekv.w;
            float g = ekb;
            if (!first) {
                const float4 g4 = *(const float4*)redG[q ^ 1][quad * 4 + reg];
                g += rn[reg] * (g4.x + g4.y + g4.z + g4.w);
            }
            gate[reg] = 1.f / (1.f + __expf(-g));
        }

        // ---- update + f16 h write + norm partial ----
        const int pw = p ^ 1;
        float pn[4];
        #pragma unroll
        for (int reg = 0; reg < 4; ++reg) {
            const int row = quad * 4 + reg;
            float sq = 0.f;
            #pragma unroll
            for (int sub = 0; sub < NSUB; ++sub) {
                const float asum = acc[sub][0][reg] + acc[sub][1][reg];
                float ht = rn[reg] * asum + keysVc[reg][sub] + eWc[sub];
                ht = fmaxf(ht, 0.f);
                const float u2 = rn[reg] * upv[reg][sub] + gate[reg] * ht;
                upv[reg][sub] = u2;
                sq += u2 * u2;
                hF[pw][row][wave * 64 + sub * 16 + n] = h_bits((_Float16)u2);
            }
            pn[reg] = sq;
        }

        // reload step-invariants in place
        if (sn >= 0) {
            const size_t eo = (size_t)(b * S + sn) * D;
            #pragma unroll
            for (int sub = 0; sub < NSUB; ++sub)
                eWc[sub] = eWp[eo + wave * 64 + sub * 16 + n];
            ekv = *(const float4*)(ek + (size_t)(b * S + sn) * K + kh + quad * 4);
        }

        // gate-dot partial for next step
        float gd[4];
        #pragma unroll
        for (int reg = 0; reg < 4; ++reg) {
            float v = 0.f;
            #pragma unroll
            for (int sub = 0; sub < NSUB; ++sub)
                v += upv[reg][sub] * e_n[sub];
            gd[reg] = v;
        }
        #pragma unroll
        for (int m = 1; m <= 8; m <<= 1) {
            #pragma unroll
            for (int reg = 0; reg < 4; ++reg) {
                pn[reg] += __shfl_xor(pn[reg], m);
                gd[reg] += __shfl_xor(gd[reg], m);
            }
        }
        if (n == 0) {
            #pragma unroll
            for (int reg = 0; reg < 4; ++reg) {
                redN[q][quad * 4 + reg][wave] = pn[reg];
                redG[q][quad * 4 + reg][wave] = gd[reg];
            }
        }

        __syncthreads();   // the ONLY barrier

        #pragma unroll
        for (int reg = 0; reg < 4; ++reg) {
            const float4 r4 = *(const float4*)redN[q][quad * 4 + reg];
            rn[reg] = rsqrtf(fmaxf(r4.x + r4.y + r4.z + r4.w, 1e-12f));
        }
        p ^= 1; q ^= 1; first = false;
    }

    #pragma unroll
    for (int reg = 0; reg < 4; ++reg) {
        const size_t base = (size_t)(b * K + kh + quad * 4 + reg) * D;
        #pragma unroll
        for (int sub = 0; sub < NSUB; ++sub)
            out[base + wave * 64 + sub * 16 + n] = rn[reg] * upv[reg][sub];
    }
}

extern "C" void kernel_launch(void* const* d_in, const int* in_sizes, int n_in,
                              void* d_out, int out_size, void* d_ws, size_t ws_size,
                              hipStream_t stream) {
    const int*   prgrph = (const int*)d_in[0];
    const void*  pmask  = d_in[1];
    const float* keys   = (const float*)d_in[2];
    const float* E      = (const float*)d_in[3];
    const float* U      = (const float*)d_in[4];
    const float* V      = (const float*)d_in[5];
    const float* W      = (const float*)d_in[6];
    float* out = (float*)d_out;

    float* ws_enc   = (float*)d_ws;                          // B*S*D  (8 MB)
    float* ws_eW    = ws_enc + (size_t)B * S * D;            // B*S*D  (8 MB)
    float* ws_keysV = ws_eW  + (size_t)B * S * D;            // B*K*D  (4 MB)
    float* ws_ek    = ws_keysV + (size_t)B * K * D;          // B*S*K  (1 MB)
    int*   ws_mask  = (int*)(ws_ek + (size_t)B * S * K);     // B*S

    mask_kernel<<<1, 256, 0, stream>>>(pmask, ws_mask);
    prep_kernel<<<B * 2, 256, 0, stream>>>(prgrph, E, W, keys,
                                           ws_enc, ws_eW, ws_ek);
    gemm_f32_kernel<<<(B * K) / 32, 256, 0, stream>>>(keys, V, ws_keysV);
    recur_kernel<<<B * (K / KH), 256, 0, stream>>>(
        ws_enc, ws_eW, ws_keysV, ws_ek, U, ws_mask, out);
}